// Round 8
// baseline (1153.355 us; speedup 1.0000x reference)
//
#include <hip/hip_runtime.h>
#include <hip/hip_fp16.h>
#include <cstdint>
#include <cstddef>

// OwnVanillaRNN R8: weight-stationary with EXPLICIT AGPR pinning.
// R3-R7 revealed: allocator grants exactly HALF the legal VGPR budget
// (128 @ 8 waves/CU, 64 @ 16 waves/CU) -- the other half is the AGPR class.
// So: 512 thr, thread = (row-group g: 4 rows, slice s: 144 dims).
// 72 uint4 weight frags/thread: 21 VGPR + 32 AGPR (v_accvgpr_write/read asm)
// + 19 LDS (152 KB). Per step: 18 h-broadcast b128 (shared by 4 rows),
// 19 LDS weight reads, 288 v_dot2_f32_f16, 128 volatile accvgpr_read
// (re-materialized each step -> no VGPR live range). Quad-DPP K-reduce,
// double-buffered h, ONE barrier/step.

constexpr int BATCH = 256;
constexpr int SEQ   = 512;
constexpr int IN    = 64;
constexpr int HID   = 512;
constexpr int OUT   = 64;
constexpr int T     = 512;         // threads per block
constexpr int DTOT  = HID + IN;    // 576
constexpr int DSL   = DTOT / 4;    // 144 dims per slice
constexpr int F_LDS0 = 53;         // frags 53..71 live in LDS (19)
constexpr int N_LDSF = 19;

typedef _Float16 half2v __attribute__((ext_vector_type(2)));

__device__ __forceinline__ float fdot2(uint32_t w, uint32_t h, float acc) {
    return __builtin_amdgcn_fdot2(__builtin_bit_cast(half2v, w),
                                  __builtin_bit_cast(half2v, h), acc, false);
}
__device__ __forceinline__ uint32_t packh2(float lo, float hi) {
    return (uint32_t)__half_as_ushort(__float2half(lo)) |
           ((uint32_t)__half_as_ushort(__float2half(hi)) << 16);
}
template <int CTRL>
__device__ __forceinline__ float dpp_add(float v) {
    int i = __builtin_bit_cast(int, v);
    int p = __builtin_amdgcn_update_dpp(i, i, CTRL, 0xF, 0xF, false);
    return v + __builtin_bit_cast(float, p);
}

// Frag k (0..71): p = k>>2 (h-position), r = k&3 (row within group).
// Thread t: g = t>>2, s = t&3. Weight = W[4g+r][144 s + 8 p .. +7] as 8 f16.
__global__ __launch_bounds__(256, 1)
void prep_w(const float* __restrict__ Wh, const float* __restrict__ Wx,
            uint4* __restrict__ Wpk) {
    const int idx = blockIdx.x * 256 + threadIdx.x;   // 72*512
    const int k = idx >> 9, t = idx & (T - 1);
    const int p = k >> 2, r = k & 3;
    const int g = t >> 2, s = t & 3;
    const int o = 4 * g + r;
    const int j = DSL * s + 8 * p;   // never straddles the 512 boundary
    const float* src = (j < HID) ? (Wh + (size_t)o * HID + j)
                                 : (Wx + (size_t)o * IN + (j - HID));
    uint4 d;
    d.x = packh2(src[0], src[1]);
    d.y = packh2(src[2], src[3]);
    d.z = packh2(src[4], src[5]);
    d.w = packh2(src[6], src[7]);
    Wpk[idx] = d;
}

#define WV_LIST(M) \
  M(0)  M(1)  M(2)  M(3)  M(4)  M(5)  M(6)  M(7)  M(8)  M(9)  M(10) \
  M(11) M(12) M(13) M(14) M(15) M(16) M(17) M(18) M(19) M(20)
#define AG_LIST(M) \
  M(21) M(22) M(23) M(24) M(25) M(26) M(27) M(28) M(29) M(30) M(31) \
  M(32) M(33) M(34) M(35) M(36) M(37) M(38) M(39) M(40) M(41) M(42) \
  M(43) M(44) M(45) M(46) M(47) M(48) M(49) M(50) M(51) M(52)

// MAC helpers: hv must be in scope.
#define MV(f, acc) { \
    acc = fdot2(w##f.x, hv.x, acc); acc = fdot2(w##f.y, hv.y, acc); \
    acc = fdot2(w##f.z, hv.z, acc); acc = fdot2(w##f.w, hv.w, acc); }
#define MA(f, acc) { uint32_t q0, q1, q2, q3; \
    asm volatile("v_accvgpr_read_b32 %0, %1" : "=v"(q0) : "a"(ag##f##_0)); \
    asm volatile("v_accvgpr_read_b32 %0, %1" : "=v"(q1) : "a"(ag##f##_1)); \
    asm volatile("v_accvgpr_read_b32 %0, %1" : "=v"(q2) : "a"(ag##f##_2)); \
    asm volatile("v_accvgpr_read_b32 %0, %1" : "=v"(q3) : "a"(ag##f##_3)); \
    acc = fdot2(q0, hv.x, acc); acc = fdot2(q1, hv.y, acc); \
    acc = fdot2(q2, hv.z, acc); acc = fdot2(q3, hv.w, acc); }
#define ML(f, acc) { const uint4 wv = wl[(size_t)((f) - F_LDS0) * T + t]; \
    acc = fdot2(wv.x, hv.x, acc); acc = fdot2(wv.y, hv.y, acc); \
    acc = fdot2(wv.z, hv.z, acc); acc = fdot2(wv.w, hv.w, acc); }

__global__ __launch_bounds__(T, 2)
__attribute__((amdgpu_waves_per_eu(2, 2)))
void rnn_main(const float* __restrict__ x,  const float* __restrict__ bx,
              const float* __restrict__ bh, const float* __restrict__ Wy,
              const float* __restrict__ by, const uint4* __restrict__ Wpk,
              float* __restrict__ y) {
    __shared__ uint4 wl[N_LDSF * T];                 // 152 KB weights
    __shared__ __align__(16) __half hb2[2][DTOT];    // double-buffered h~

    const int b = blockIdx.x, t = threadIdx.x;
    const int g = t >> 2, s = t & 3;

    // ---- one-time: LDS weights ----
    #pragma unroll
    for (int i = 0; i < N_LDSF; ++i)
        wl[i * T + t] = Wpk[(size_t)(F_LDS0 + i) * T + t];

    // ---- one-time: VGPR frags (named SSA) ----
#define DECL_WV(f) uint4 w##f = Wpk[(size_t)(f) * T + t];
    WV_LIST(DECL_WV)
#undef DECL_WV

    // ---- one-time: AGPR frags (explicit accvgpr_write) ----
#define DECL_AG(f) uint32_t ag##f##_0, ag##f##_1, ag##f##_2, ag##f##_3;
    AG_LIST(DECL_AG)
#undef DECL_AG
#define LOAD_AG(f) { const uint4 tmp = Wpk[(size_t)(f) * T + t]; \
    asm volatile("v_accvgpr_write_b32 %0, %1" : "=a"(ag##f##_0) : "v"(tmp.x)); \
    asm volatile("v_accvgpr_write_b32 %0, %1" : "=a"(ag##f##_1) : "v"(tmp.y)); \
    asm volatile("v_accvgpr_write_b32 %0, %1" : "=a"(ag##f##_2) : "v"(tmp.z)); \
    asm volatile("v_accvgpr_write_b32 %0, %1" : "=a"(ag##f##_3) : "v"(tmp.w)); }
    AG_LIST(LOAD_AG)
#undef LOAD_AG

    const float bb0 = bx[4 * g + 0] + bh[4 * g + 0];
    const float bb1 = bx[4 * g + 1] + bh[4 * g + 1];
    const float bb2 = bx[4 * g + 2] + bh[4 * g + 2];
    const float bb3 = bx[4 * g + 3] + bh[4 * g + 3];
    const float* xb = x + (size_t)b * SEQ * IN;

    hb2[0][t] = __float2half(0.0f);                     // h0 = 0 (t covers 512)
    if (t < IN) hb2[0][HID + t] = __float2half(xb[t]);  // x_0
    float xv = (t < IN) ? xb[IN + t] : 0.0f;            // x_1 prefetched
    __syncthreads();

    #pragma unroll 1
    for (int tt = 0; tt < SEQ; ++tt) {
        const int c = tt & 1;
        const uint4* hbv =
            (const uint4*)((const __half*)hb2[c] + DSL * s);  // slice base
        float a0 = 0.f, a1 = 0.f, a2 = 0.f, a3 = 0.f;

        { const uint4 hv = hbv[0];  MV(0,a0)  MV(1,a1)  MV(2,a2)  MV(3,a3)  }
        { const uint4 hv = hbv[1];  MV(4,a0)  MV(5,a1)  MV(6,a2)  MV(7,a3)  }
        { const uint4 hv = hbv[2];  MV(8,a0)  MV(9,a1)  MV(10,a2) MV(11,a3) }
        { const uint4 hv = hbv[3];  MV(12,a0) MV(13,a1) MV(14,a2) MV(15,a3) }
        { const uint4 hv = hbv[4];  MV(16,a0) MV(17,a1) MV(18,a2) MV(19,a3) }
        { const uint4 hv = hbv[5];  MV(20,a0) MA(21,a1) MA(22,a2) MA(23,a3) }
        { const uint4 hv = hbv[6];  MA(24,a0) MA(25,a1) MA(26,a2) MA(27,a3) }
        { const uint4 hv = hbv[7];  MA(28,a0) MA(29,a1) MA(30,a2) MA(31,a3) }
        { const uint4 hv = hbv[8];  MA(32,a0) MA(33,a1) MA(34,a2) MA(35,a3) }
        { const uint4 hv = hbv[9];  MA(36,a0) MA(37,a1) MA(38,a2) MA(39,a3) }
        { const uint4 hv = hbv[10]; MA(40,a0) MA(41,a1) MA(42,a2) MA(43,a3) }
        { const uint4 hv = hbv[11]; MA(44,a0) MA(45,a1) MA(46,a2) MA(47,a3) }
        { const uint4 hv = hbv[12]; MA(48,a0) MA(49,a1) MA(50,a2) MA(51,a3) }
        { const uint4 hv = hbv[13]; MA(52,a0) ML(53,a1) ML(54,a2) ML(55,a3) }
        { const uint4 hv = hbv[14]; ML(56,a0) ML(57,a1) ML(58,a2) ML(59,a3) }
        { const uint4 hv = hbv[15]; ML(60,a0) ML(61,a1) ML(62,a2) ML(63,a3) }
        { const uint4 hv = hbv[16]; ML(64,a0) ML(65,a1) ML(66,a2) ML(67,a3) }
        { const uint4 hv = hbv[17]; ML(68,a0) ML(69,a1) ML(70,a2) ML(71,a3) }

        // 4-way K-reduce within each quad (lanes = the 4 slices of group g)
        a0 = dpp_add<0xB1>(a0); a0 = dpp_add<0x4E>(a0);
        a1 = dpp_add<0xB1>(a1); a1 = dpp_add<0x4E>(a1);
        a2 = dpp_add<0xB1>(a2); a2 = dpp_add<0x4E>(a2);
        a3 = dpp_add<0xB1>(a3); a3 = dpp_add<0x4E>(a3);

        if (s == 0) {
            float z0 = fminf(fmaxf(a0 + bb0, -15.f), 15.f);
            float z1 = fminf(fmaxf(a1 + bb1, -15.f), 15.f);
            float z2 = fminf(fmaxf(a2 + bb2, -15.f), 15.f);
            float z3 = fminf(fmaxf(a3 + bb3, -15.f), 15.f);
            const float h0 = 1.f - 2.f * __builtin_amdgcn_rcpf(__expf(2.f * z0) + 1.f);
            const float h1 = 1.f - 2.f * __builtin_amdgcn_rcpf(__expf(2.f * z1) + 1.f);
            const float h2 = 1.f - 2.f * __builtin_amdgcn_rcpf(__expf(2.f * z2) + 1.f);
            const float h3 = 1.f - 2.f * __builtin_amdgcn_rcpf(__expf(2.f * z3) + 1.f);
            uint2 pk;
            pk.x = packh2(h0, h1);
            pk.y = packh2(h2, h3);
            ((uint2*)hb2[c ^ 1])[g] = pk;             // rows 4g..4g+3
        }
        if (t < IN) {
            hb2[c ^ 1][HID + t] = __float2half(xv);   // x_{tt+1}
            if (tt + 2 < SEQ) xv = xb[(size_t)(tt + 2) * IN + t];
        }
        __syncthreads();
    }

    // ---- epilogue: y = h_T @ Wy^T + by (final h is in buffer 0) ----
    if (t < OUT) {
        float acc = by[t];
        const float* wy = Wy + (size_t)t * HID;
        #pragma unroll 8
        for (int j = 0; j < HID; ++j)
            acc = fmaf(wy[j], __half2float(hb2[0][j]), acc);
        y[(size_t)b * OUT + t] = acc;
    }
}

extern "C" void kernel_launch(void* const* d_in, const int* in_sizes, int n_in,
                              void* d_out, int out_size, void* d_ws, size_t ws_size,
                              hipStream_t stream) {
    const float* x  = (const float*)d_in[0];
    const float* Wx = (const float*)d_in[1];
    const float* bx = (const float*)d_in[2];
    const float* Wh = (const float*)d_in[3];
    const float* bh = (const float*)d_in[4];
    const float* Wy = (const float*)d_in[5];
    const float* by = (const float*)d_in[6];
    float* y = (float*)d_out;

    uint4* Wpk = (uint4*)d_ws;  // 72*512*16 B = 576 KB packed f16 fragments

    hipLaunchKernelGGL(prep_w, dim3(72 * T / 256), dim3(256), 0, stream,
                       Wh, Wx, Wpk);
    hipLaunchKernelGGL(rnn_main, dim3(BATCH), dim3(T), 0, stream,
                       x, bx, bh, Wy, by, Wpk, y);
}